// Round 1
// baseline (63.683 us; speedup 1.0000x reference)
//
#include <hip/hip_runtime.h>

#define Nn 512
#define Dd 128
#define Kk 2048
constexpr float INV_T = 1.0f / 0.07f;

__global__ __launch_bounds__(256) void row_kernel(
    const float* __restrict__ q, const float* __restrict__ k,
    const float* __restrict__ queue, const int* __restrict__ labels,
    float* __restrict__ row_loss)
{
    const int n = blockIdx.x;
    const int t = threadIdx.x;
    __shared__ float sq[Dd];
    __shared__ float red[256];

    // Stage q row in LDS; partial products for l_pos
    float lp = 0.f;
    if (t < Dd) {
        float qv = q[n * Dd + t];
        sq[t] = qv;
        lp = qv * k[n * Dd + t];
    }
    red[t] = lp;
    __syncthreads();
    for (int s = 128; s > 0; s >>= 1) {
        if (t < s) red[t] += red[t + s];
        __syncthreads();
    }
    const float lpos = red[0] * INV_T;
    __syncthreads();

    const int c = labels[n];
    const float* base = queue + (size_t)c * Dd * Kk + t * 8;

    float acc[8] = {0, 0, 0, 0, 0, 0, 0, 0};
    #pragma unroll 4
    for (int d = 0; d < Dd; ++d) {
        const float qd = sq[d];
        const float4* p = reinterpret_cast<const float4*>(base + (size_t)d * Kk);
        float4 a = p[0];
        float4 b = p[1];
        acc[0] += qd * a.x; acc[1] += qd * a.y;
        acc[2] += qd * a.z; acc[3] += qd * a.w;
        acc[4] += qd * b.x; acc[5] += qd * b.y;
        acc[6] += qd * b.z; acc[7] += qd * b.w;
    }

    // logits in registers; block max (include lpos)
    float m = lpos;
    #pragma unroll
    for (int j = 0; j < 8; ++j) { acc[j] *= INV_T; m = fmaxf(m, acc[j]); }
    red[t] = m;
    __syncthreads();
    for (int s = 128; s > 0; s >>= 1) {
        if (t < s) red[t] = fmaxf(red[t], red[t + s]);
        __syncthreads();
    }
    m = red[0];
    __syncthreads();

    float es = 0.f;
    #pragma unroll
    for (int j = 0; j < 8; ++j) es += expf(acc[j] - m);
    red[t] = es;
    __syncthreads();
    for (int s = 128; s > 0; s >>= 1) {
        if (t < s) red[t] += red[t + s];
        __syncthreads();
    }
    if (t == 0) {
        const float lse = logf(red[0] + expf(lpos - m)) + m;
        row_loss[n] = lse - lpos;
    }
}

__global__ __launch_bounds__(256) void reduce_kernel(
    const float* __restrict__ row_loss, float* __restrict__ out)
{
    __shared__ float red[256];
    const int t = threadIdx.x;
    red[t] = row_loss[t] + row_loss[t + 256];
    __syncthreads();
    for (int s = 128; s > 0; s >>= 1) {
        if (t < s) red[t] += red[t + s];
        __syncthreads();
    }
    if (t == 0) out[0] = red[0] / (float)Nn;
}

extern "C" void kernel_launch(void* const* d_in, const int* in_sizes, int n_in,
                              void* d_out, int out_size, void* d_ws, size_t ws_size,
                              hipStream_t stream) {
    const float* q      = (const float*)d_in[0];
    const float* k      = (const float*)d_in[1];
    const float* queue  = (const float*)d_in[2];
    // d_in[3] = class_weights — unused by the reference computation
    const int* labels   = (const int*)d_in[4];
    float* out          = (float*)d_out;
    float* row_loss     = (float*)d_ws;   // 512 floats

    row_kernel<<<Nn, 256, 0, stream>>>(q, k, queue, labels, row_loss);
    reduce_kernel<<<1, 256, 0, stream>>>(row_loss, out);
}

// Round 2
// 51.924 us; speedup vs baseline: 1.2265x; 1.2265x over previous
//
#include <hip/hip_runtime.h>

#define Nn 512
#define Dd 128
#define Kk 2048
#define Cc 100
#define KC 4            // k-chunks per class
#define CHUNK 512       // cols per chunk = 256 threads * 2
#define G 8             // samples per pass
constexpr float INV_T = 1.0f / 0.07f;

// ws layout (floats):
// [0, 512)              lpos[n]
// [512, 512+2048)       stats_m[n*KC+kc]
// [2560, 4608)          stats_s[n*KC+kc]

__global__ __launch_bounds__(256) void chunk_kernel(
    const float* __restrict__ q, const float* __restrict__ k,
    const float* __restrict__ queue, const int* __restrict__ labels,
    float* __restrict__ ws)
{
    const int c    = blockIdx.y;
    const int kc   = blockIdx.x;
    const int t    = threadIdx.x;
    const int lane = t & 63;
    const int wid  = t >> 6;

    __shared__ int   s_list[Nn];
    __shared__ int   s_cnt;
    __shared__ float sq[Dd][G];     // staged q rows, [d][s]
    __shared__ float wred[G][4];    // per-wave partials
    __shared__ float bmaxs[G];

    // wave-0 ballot scan: deterministic ordered list of samples with label c
    if (t < 64) {
        int cnt = 0;
        for (int base = 0; base < Nn; base += 64) {
            int lab = labels[base + t];
            unsigned long long m = __ballot(lab == c);
            if (lab == c) {
                int pos = __popcll(m & ((1ull << t) - 1ull));
                s_list[cnt + pos] = base + t;
            }
            cnt += __popcll(m);
        }
        if (t == 0) s_cnt = cnt;
    }
    __syncthreads();
    const int cnt = s_cnt;
    if (cnt == 0) return;

    float* lpos    = ws;
    float* stats_m = ws + Nn;
    float* stats_s = ws + Nn + Nn * KC;

    const int col0 = kc * CHUNK + t * 2;
    const float* qbase = queue + (size_t)c * ((size_t)Dd * Kk) + col0;

    for (int g0 = 0; g0 < cnt; g0 += G) {
        const int gs = min(G, cnt - g0);

        // stage q rows: sq[d][s] = q[list[g0+s]][d]
        for (int i = t; i < Dd * G; i += 256) {
            int d = i >> 3, s = i & 7;
            sq[d][s] = (s < gs) ? q[s_list[g0 + s] * Dd + d] : 0.f;
        }
        __syncthreads();

        float lx[G], ly[G];
        {
            float2 acc[G];
            #pragma unroll
            for (int s = 0; s < G; ++s) acc[s] = make_float2(0.f, 0.f);
            const float* p = qbase;
            #pragma unroll 4
            for (int d = 0; d < Dd; ++d) {
                float2 v = *reinterpret_cast<const float2*>(p);
                p += Kk;
                #pragma unroll
                for (int s = 0; s < G; ++s) {
                    float qd = sq[d][s];
                    acc[s].x = fmaf(qd, v.x, acc[s].x);
                    acc[s].y = fmaf(qd, v.y, acc[s].y);
                }
            }
            #pragma unroll
            for (int s = 0; s < G; ++s) { lx[s] = acc[s].x * INV_T; ly[s] = acc[s].y * INV_T; }
        }

        // per-sample block max over this chunk's 512 logits
        #pragma unroll
        for (int s = 0; s < G; ++s) {
            if (s < gs) {
                float v = fmaxf(lx[s], ly[s]);
                #pragma unroll
                for (int off = 32; off >= 1; off >>= 1)
                    v = fmaxf(v, __shfl_xor(v, off, 64));
                if (lane == 0) wred[s][wid] = v;
            }
        }
        __syncthreads();
        if (t < gs)
            bmaxs[t] = fmaxf(fmaxf(wred[t][0], wred[t][1]), fmaxf(wred[t][2], wred[t][3]));
        __syncthreads();

        // per-sample exp-sum
        #pragma unroll
        for (int s = 0; s < G; ++s) {
            if (s < gs) {
                float bm = bmaxs[s];
                float e = expf(lx[s] - bm) + expf(ly[s] - bm);
                #pragma unroll
                for (int off = 32; off >= 1; off >>= 1)
                    e += __shfl_xor(e, off, 64);
                if (lane == 0) wred[s][wid] = e;
            }
        }
        __syncthreads();

        if (t < gs) {
            int n = s_list[g0 + t];
            stats_m[n * KC + kc] = bmaxs[t];
            stats_s[n * KC + kc] = wred[t][0] + wred[t][1] + wred[t][2] + wred[t][3];
            if (kc == 0) {
                // l_pos for this sample (q row already staged in sq[.][t])
                float lp = 0.f;
                const float* krow = k + n * Dd;
                #pragma unroll 8
                for (int d = 0; d < Dd; ++d) lp = fmaf(sq[d][t], krow[d], lp);
                lpos[n] = lp * INV_T;
            }
        }
        __syncthreads();
    }
}

__global__ __launch_bounds__(512) void finish_kernel(
    const float* __restrict__ ws, float* __restrict__ out)
{
    const int t = threadIdx.x;   // one thread per sample, 512 threads
    const float* lpos    = ws;
    const float* stats_m = ws + Nn;
    const float* stats_s = ws + Nn + Nn * KC;

    const float lp = lpos[t];
    float mm[KC], ss[KC];
    float m = lp;
    #pragma unroll
    for (int j = 0; j < KC; ++j) {
        mm[j] = stats_m[t * KC + j];
        ss[j] = stats_s[t * KC + j];
        m = fmaxf(m, mm[j]);
    }
    float sum = expf(lp - m);
    #pragma unroll
    for (int j = 0; j < KC; ++j) sum += ss[j] * expf(mm[j] - m);
    const float loss = logf(sum) + m - lp;

    __shared__ float red[512];
    red[t] = loss;
    __syncthreads();
    for (int s2 = 256; s2 > 0; s2 >>= 1) {
        if (t < s2) red[t] += red[t + s2];
        __syncthreads();
    }
    if (t == 0) out[0] = red[0] / (float)Nn;
}

extern "C" void kernel_launch(void* const* d_in, const int* in_sizes, int n_in,
                              void* d_out, int out_size, void* d_ws, size_t ws_size,
                              hipStream_t stream) {
    const float* q      = (const float*)d_in[0];
    const float* k      = (const float*)d_in[1];
    const float* queue  = (const float*)d_in[2];
    // d_in[3] = class_weights — unused by the reference computation
    const int* labels   = (const int*)d_in[4];
    float* out          = (float*)d_out;
    float* ws           = (float*)d_ws;

    dim3 grid(KC, Cc);
    chunk_kernel<<<grid, 256, 0, stream>>>(q, k, queue, labels, ws);
    finish_kernel<<<1, 512, 0, stream>>>(ws, out);
}